// Round 2
// baseline (283.403 us; speedup 1.0000x reference)
//
#include <hip/hip_runtime.h>

// FWEnergyGAD: element-wise double-well energy + forces + GAD direction +
// 2x2 Hessian eigendecomposition (closed form).
//
// Outputs concatenated flat in return order (n = B = 4194304):
//   [0,     n)   energy
//   [n,    3n)   forces      (B,2)
//   [3n,   5n)   energy_grad (B,2)
//   [5n,   9n)   hessian     (B,2,2)
//   [9n,  10n)   eigenval 0  (smaller)
//   [10n, 11n)   eigenval 1  (larger)
//
// R2: 4 points/thread, all memory ops are 16B vector + nontemporal (output is
// a 184 MB write-once stream; don't thrash 32 MB L2).

typedef float f32x4 __attribute__((ext_vector_type(4)));

__global__ __launch_bounds__(256) void fw_energy_gad_kernel(
    const f32x4* __restrict__ in4, float* __restrict__ out, int n4) {
    int j = blockIdx.x * blockDim.x + threadIdx.x;
    if (j >= n4) return;

    const float BETA = 0.1f;

    // 2 x float4 = 4 points (u,v interleaved)
    f32x4 a0 = __builtin_nontemporal_load(in4 + 2 * (size_t)j);
    f32x4 a1 = __builtin_nontemporal_load(in4 + 2 * (size_t)j + 1);

    float ux[4] = {a0.x, a0.z, a1.x, a1.z};
    float vx[4] = {a0.y, a0.w, a1.y, a1.w};

    float e[4], fx[4], fy[4], gadx[4], gady[4], hxx[4], hyy[4], l0[4], l1[4];

#pragma unroll
    for (int k = 0; k < 4; ++k) {
        float u = ux[k] - 0.5f;
        float v = vx[k] - 0.5f;
        float uu = u * u;
        float vv = v * v;
        float a = uu - 1.0f;
        float b = vv - 1.0f;

        e[k] = a * a + b * b + BETA * u * v;

        float gx = 4.0f * u * a + BETA * v;
        float gy = 4.0f * v * b + BETA * u;
        float fxx = -gx;
        float fyy = -gy;
        fx[k] = fxx;
        fy[k] = fyy;

        float hx = 12.0f * uu - 4.0f;
        float hy = 12.0f * vv - 4.0f;
        hxx[k] = hx;
        hyy[k] = hy;

        // 2x2 symmetric eigh, closed form; hxy = BETA so r >= 0.1 always.
        float d = 0.5f * (hx - hy);
        float m = 0.5f * (hx + hy);
        float r = sqrtf(d * d + BETA * BETA);
        l0[k] = m - r;
        l1[k] = m + r;

        // Eigenvector of l0; branch avoids r-|d| cancellation.
        float wxp = BETA, wyp = -(d + r);   // d >= 0 branch
        float wxn = d - r, wyn = BETA;      // d <  0 branch
        bool pos = d >= 0.0f;
        float wx = pos ? wxp : wxn;
        float wy = pos ? wyp : wyn;
        float n2 = wx * wx + wy * wy;       // >= 0.01

        // gad = -f + 2 (f.w)/(w.w) w  (sign of w irrelevant)
        float fd = fxx * wx + fyy * wy;
        float s = 2.0f * fd / n2;
        float gxv = -fxx + s * wx;
        float gyv = -fyy + s * wy;

        float prod = l0[k] * l1[k];
        float gmag = sqrtf(gxv * gxv + gyv * gyv);
        if (prod > 0.0f && gmag < 1.0f) {
            float inv = 1.0f / fmaxf(gmag, 1e-30f);
            gxv *= inv;
            gyv *= inv;
        }
        gadx[k] = gxv;   // TAU = 1 -> energy_grad == gad
        gady[k] = gyv;
    }

    size_t N = (size_t)n4 * 4;
    size_t jj = (size_t)j;

    // energy: 1 x float4
    f32x4 ev = {e[0], e[1], e[2], e[3]};
    __builtin_nontemporal_store(ev, (f32x4*)out + jj);

    // forces: 2 x float4
    f32x4* f4 = (f32x4*)(out + N);
    f32x4 fv0 = {fx[0], fy[0], fx[1], fy[1]};
    f32x4 fv1 = {fx[2], fy[2], fx[3], fy[3]};
    __builtin_nontemporal_store(fv0, f4 + 2 * jj);
    __builtin_nontemporal_store(fv1, f4 + 2 * jj + 1);

    // energy_grad: 2 x float4
    f32x4* g4 = (f32x4*)(out + 3 * N);
    f32x4 gv0 = {gadx[0], gady[0], gadx[1], gady[1]};
    f32x4 gv1 = {gadx[2], gady[2], gadx[3], gady[3]};
    __builtin_nontemporal_store(gv0, g4 + 2 * jj);
    __builtin_nontemporal_store(gv1, g4 + 2 * jj + 1);

    // hessian: 4 x float4 (hxx, BETA, BETA, hyy per point)
    f32x4* h4 = (f32x4*)(out + 5 * N);
#pragma unroll
    for (int k = 0; k < 4; ++k) {
        f32x4 hv = {hxx[k], BETA, BETA, hyy[k]};
        __builtin_nontemporal_store(hv, h4 + 4 * jj + k);
    }

    // eigenvalues: 1 x float4 each
    f32x4 l0v = {l0[0], l0[1], l0[2], l0[3]};
    f32x4 l1v = {l1[0], l1[1], l1[2], l1[3]};
    __builtin_nontemporal_store(l0v, (f32x4*)(out + 9 * N) + jj);
    __builtin_nontemporal_store(l1v, (f32x4*)(out + 10 * N) + jj);
}

extern "C" void kernel_launch(void* const* d_in, const int* in_sizes, int n_in,
                              void* d_out, int out_size, void* d_ws, size_t ws_size,
                              hipStream_t stream) {
    const f32x4* in4 = (const f32x4*)d_in[0];
    float* out = (float*)d_out;
    int n = in_sizes[0] / 2;   // B points
    int n4 = n / 4;            // 4 points per thread (B divisible by 4)

    int block = 256;
    int grid = (n4 + block - 1) / block;
    fw_energy_gad_kernel<<<grid, block, 0, stream>>>(in4, out, n4);
}

// Round 4
// 203.153 us; speedup vs baseline: 1.3950x; 1.3950x over previous
//
#include <hip/hip_runtime.h>

// FWEnergyGAD: element-wise double-well energy + forces + GAD direction +
// 2x2 Hessian eigendecomposition (closed form).
//
// Outputs concatenated flat in return order (n = B = 4194304):
//   [0,     n)   energy
//   [n,    3n)   forces      (B,2)
//   [3n,   5n)   energy_grad (B,2)
//   [5n,   9n)   hessian     (B,2,2)
//   [9n,  10n)   eigenval 0  (smaller)
//   [10n, 11n)   eigenval 1  (larger)
//
// R4 (= R3 with ext_vector_type, HIP_vector_type rejected by the builtin):
// 1 point/thread, every store instruction is per-LANE contiguous
// (lane i -> base + i*width, fully covered cache lines: no partial-line
// writes, no read-for-ownership) + nontemporal hint (output is write-once,
// don't allocate 184 MB in L2). R2's per-THREAD-contiguous nt stores were
// 1/2- and 1/4-density per instruction -> WRITE_SIZE 311 MB vs 184.5 ideal.

typedef float f32x2 __attribute__((ext_vector_type(2)));
typedef float f32x4 __attribute__((ext_vector_type(4)));

__global__ __launch_bounds__(256) void fw_energy_gad_kernel(
    const f32x2* __restrict__ in, float* __restrict__ out, int n) {
    int i = blockIdx.x * blockDim.x + threadIdx.x;
    if (i >= n) return;

    const float BETA = 0.1f;

    f32x2 p = in[i];
    float u = p.x - 0.5f;
    float v = p.y - 0.5f;
    float uu = u * u;
    float vv = v * v;
    float a = uu - 1.0f;   // u^2 - 1
    float b = vv - 1.0f;   // v^2 - 1

    float energy = a * a + b * b + BETA * u * v;

    float gx = 4.0f * u * a + BETA * v;
    float gy = 4.0f * v * b + BETA * u;
    float fx = -gx;
    float fy = -gy;

    float hxx = 12.0f * uu - 4.0f;
    float hyy = 12.0f * vv - 4.0f;

    // 2x2 symmetric eigh, closed form; hxy = BETA so r >= 0.1 (never degen).
    float d = 0.5f * (hxx - hyy);
    float m = 0.5f * (hxx + hyy);
    float r = sqrtf(d * d + BETA * BETA);
    float l0 = m - r;   // smaller
    float l1 = m + r;   // larger

    // Eigenvector of l0; branch picked to avoid r-|d| cancellation.
    bool pos = d >= 0.0f;
    float wx = pos ? BETA : (d - r);
    float wy = pos ? -(d + r) : BETA;
    float n2 = wx * wx + wy * wy;   // >= 0.01

    // gad = -f + 2 (f.w)/(w.w) w  (sign of w irrelevant; quadratic)
    float fd = fx * wx + fy * wy;
    float s = 2.0f * fd / n2;
    float gadx = -fx + s * wx;
    float gady = -fy + s * wy;

    float prod = l0 * l1;
    float gmag = sqrtf(gadx * gadx + gady * gady);
    bool norm = (prod > 0.0f) && (gmag < 1.0f);
    float inv = norm ? (1.0f / fmaxf(gmag, 1e-30f)) : 1.0f;
    gadx *= inv;
    gady *= inv;
    // TAU = 1.0 -> energy_grad == gad

    size_t N = (size_t)n;
    size_t ii = (size_t)i;

    f32x2 fv = {fx, fy};
    f32x2 gv = {gadx, gady};
    f32x4 hv = {hxx, BETA, BETA, hyy};

    __builtin_nontemporal_store(energy, out + ii);
    __builtin_nontemporal_store(fv, (f32x2*)(out + N) + ii);
    __builtin_nontemporal_store(gv, (f32x2*)(out + 3 * N) + ii);
    __builtin_nontemporal_store(hv, (f32x4*)(out + 5 * N) + ii);
    __builtin_nontemporal_store(l0, out + 9 * N + ii);
    __builtin_nontemporal_store(l1, out + 10 * N + ii);
}

extern "C" void kernel_launch(void* const* d_in, const int* in_sizes, int n_in,
                              void* d_out, int out_size, void* d_ws, size_t ws_size,
                              hipStream_t stream) {
    const f32x2* in = (const f32x2*)d_in[0];
    float* out = (float*)d_out;
    int n = in_sizes[0] / 2;   // B points

    int block = 256;
    int grid = (n + block - 1) / block;
    fw_energy_gad_kernel<<<grid, block, 0, stream>>>(in, out, n);
}

// Round 5
// 200.757 us; speedup vs baseline: 1.4117x; 1.0119x over previous
//
#include <hip/hip_runtime.h>

// FWEnergyGAD: element-wise double-well energy + forces + GAD direction +
// 2x2 Hessian eigendecomposition (closed form).
//
// Outputs concatenated flat in return order (n = B = 4194304):
//   [0,     n)   energy
//   [n,    3n)   forces      (B,2)
//   [3n,   5n)   energy_grad (B,2)
//   [5n,   9n)   hessian     (B,2,2)
//   [9n,  10n)   eigenval 0  (smaller)
//   [10n, 11n)   eigenval 1  (larger)
//
// R5: plain (cached) stores — NT regressed R4 vs R1 (203 vs 197 us; L2
// write-combining wins). 2 points/thread, the second offset by n/2, so
// EVERY memory instruction stays per-lane contiguous (full line coverage)
// while wave count halves and per-wave MLP doubles (14 stores + 2 loads).

typedef float f32x2 __attribute__((ext_vector_type(2)));
typedef float f32x4 __attribute__((ext_vector_type(4)));

__global__ __launch_bounds__(256) void fw_energy_gad_kernel(
    const f32x2* __restrict__ in, float* __restrict__ out, int half, int n) {
    int j = blockIdx.x * blockDim.x + threadIdx.x;
    if (j >= half) return;

    const float BETA = 0.1f;
    size_t N = (size_t)n;

    size_t idx[2] = {(size_t)j, (size_t)j + (size_t)half};

#pragma unroll
    for (int k = 0; k < 2; ++k) {
        size_t ii = idx[k];

        f32x2 p = in[ii];
        float u = p.x - 0.5f;
        float v = p.y - 0.5f;
        float uu = u * u;
        float vv = v * v;
        float a = uu - 1.0f;   // u^2 - 1
        float b = vv - 1.0f;   // v^2 - 1

        float energy = a * a + b * b + BETA * u * v;

        float gx = 4.0f * u * a + BETA * v;
        float gy = 4.0f * v * b + BETA * u;
        float fx = -gx;
        float fy = -gy;

        float hxx = 12.0f * uu - 4.0f;
        float hyy = 12.0f * vv - 4.0f;

        // 2x2 symmetric eigh, closed form; hxy = BETA so r >= 0.1.
        float d = 0.5f * (hxx - hyy);
        float m = 0.5f * (hxx + hyy);
        float r = sqrtf(d * d + BETA * BETA);
        float l0 = m - r;   // smaller
        float l1 = m + r;   // larger

        // Eigenvector of l0; branch avoids r-|d| cancellation.
        bool pos = d >= 0.0f;
        float wx = pos ? BETA : (d - r);
        float wy = pos ? -(d + r) : BETA;
        float n2 = wx * wx + wy * wy;   // >= 0.01

        // gad = -f + 2 (f.w)/(w.w) w  (sign of w irrelevant; quadratic)
        float fd = fx * wx + fy * wy;
        float s = 2.0f * fd / n2;
        float gadx = -fx + s * wx;
        float gady = -fy + s * wy;

        float prod = l0 * l1;
        float gmag = sqrtf(gadx * gadx + gady * gady);
        bool norm = (prod > 0.0f) && (gmag < 1.0f);
        float inv = norm ? (1.0f / fmaxf(gmag, 1e-30f)) : 1.0f;
        gadx *= inv;
        gady *= inv;
        // TAU = 1.0 -> energy_grad == gad

        f32x2 fv = {fx, fy};
        f32x2 gv = {gadx, gady};
        f32x4 hv = {hxx, BETA, BETA, hyy};

        out[ii] = energy;
        ((f32x2*)(out + N))[ii] = fv;
        ((f32x2*)(out + 3 * N))[ii] = gv;
        ((f32x4*)(out + 5 * N))[ii] = hv;
        out[9 * N + ii] = l0;
        out[10 * N + ii] = l1;
    }
}

extern "C" void kernel_launch(void* const* d_in, const int* in_sizes, int n_in,
                              void* d_out, int out_size, void* d_ws, size_t ws_size,
                              hipStream_t stream) {
    const f32x2* in = (const f32x2*)d_in[0];
    float* out = (float*)d_out;
    int n = in_sizes[0] / 2;   // B points
    int half = n / 2;          // 2 points per thread

    int block = 256;
    int grid = (half + block - 1) / block;
    fw_energy_gad_kernel<<<grid, block, 0, stream>>>(in, out, half, n);
}